// Round 4
// baseline (165.382 us; speedup 1.0000x reference)
//
#include <hip/hip_runtime.h>

// Block-sparse attention, fp16 QK + bf16 PV MFMA, deferred softmax,
// FUSED 2-way key split: one 512-thr WG (8 waves) per (qb, bh).
// This revision: SINGLE KERNEL, NO WORKSPACE. K/V are loaded as fp32 directly
// from global (L2-local via XCD remap), converted in-register (log2e folded
// into Q now), and written into the same swizzled fp16-K / transposed-bf16-V
// double-buffered LDS images as before. Hypothesis under test: the 256 MB
// workspace re-poison fill (44.5 us, 42% of total) is only enqueued because
// the kernel uses d_ws; dropping ws removes it. Worst case we still save the
// preconvert dispatch + gap.
// fp32 in/out. B=2 H=8 S=2048 D=64, BLOCK=64, nb=32.

typedef __attribute__((ext_vector_type(8))) short short8;
typedef __attribute__((ext_vector_type(4))) short short4_;
typedef __attribute__((ext_vector_type(4))) float float4_;
typedef __attribute__((ext_vector_type(8))) _Float16 half8_;

#define B_   2
#define H_   8
#define S_   2048
#define D_   64
#define NB_  32
#define LOG2E 1.4426950408889634f

__device__ __forceinline__ short f2bf(float f) {            // RNE float->bf16 bits
    union { float f; unsigned int u; } x; x.f = f;
    unsigned int r = x.u + 0x7FFFu + ((x.u >> 16) & 1u);
    return (short)(r >> 16);
}
__device__ __forceinline__ short f2bf_t(float f) {          // truncating float->bf16
    union { float f; unsigned int u; } x; x.f = f;
    return (short)(x.u >> 16);
}
__device__ __forceinline__ short f2h(float f) {
    _Float16 h = (_Float16)f;
    return __builtin_bit_cast(short, h);
}
// XOR-swizzled offset for a 64-col-short tile stored in granules of 8 shorts.
__device__ __forceinline__ int swz(int row, int gran) {
    return (row << 6) + (((gran ^ row) & 7) << 3);
}
// bijective XCD-clustering remap of a flat 512-WG id -> (bh, idx):
// XCD x (= n&7 under round-robin dispatch) owns bh {2x, 2x+1}, all 32 idx each.
__device__ __forceinline__ void wg_remap(int n, int& bh, int& idx) {
    const int xcd = n & 7;
    const int sub = n >> 3;          // 0..63
    bh  = (xcd << 1) + (sub & 1);
    idx = sub >> 1;                  // 0..31
}

// ---------------- main: 512-thr WG, fused 2-way key split, direct fp32 staging ----------------
__global__ __launch_bounds__(512, 4)
void attn_direct(const float* __restrict__ Q,
                 const float* __restrict__ K,
                 const float* __restrict__ V,
                 const float* __restrict__ Msk,
                 const int* __restrict__ Mat,
                 float* __restrict__ O) {
    // shorts: K dbuf [buf][half][4096] @0 | V dbuf @16384 | P [wave][1024] @32768
    // total 40960 shorts = 80 KB -> 2 WGs/CU. Epilogue overlays as float.
    __shared__ __align__(16) short lds[40960];

    const int tid  = threadIdx.x;
    const int wave = tid >> 6;        // 0..7
    const int half = wave >> 2;       // key half 0/1
    const int w4   = wave & 3;        // wave within half; 16-row q tile
    const int lane = tid & 63;
    const int c    = lane & 15;
    const int quad = lane >> 4;
    const int hid  = tid & 255;       // thread id within the half (staging)

    // staging coords: K row/chunk, V key/chunk (16 consecutive fp32 each)
    const int krow   = hid >> 2;
    const int kchunk = hid & 3;
    const int kd0    = kchunk << 4;
    const int vkey   = krow;          // same decomposition for V
    const int vd0    = kd0;

    int bh, qb;
    wg_remap(blockIdx.x, bh, qb);     // XCD-clustered: K/V panels L2-local
    const int b  = bh / H_;
    const size_t base = (size_t)bh * S_ * D_;

    // ---- active-block bitmask; this half takes alternating entries ----
    unsigned long long bmv = __ballot(Mat[qb * NB_ + (lane & 31)] != 0);
    unsigned int mb = (unsigned int)(bmv & 0xFFFFFFFFull);
    const int nact  = __popc(mb);
    const int niter = (nact + 1) >> 1;    // identical for both halves (kill-padded)
    unsigned int mine = 0;
    {
        unsigned int tb2 = mb; int idx = 0;
        while (tb2) {
            int k = __builtin_ctz(tb2); tb2 &= tb2 - 1;
            if ((idx & 1) == half) mine |= (1u << k);
            ++idx;
        }
    }

    // ---- prologue: stage first tile (always a REAL block -> finite LDS data) ----
    int kb; bool kill;
    if (mine) { kb = __builtin_ctz(mine); mine &= mine - 1; kill = false; }
    else      { kb = __builtin_ctz(mb); kill = true; }
    {
        const float* kg = K + base + (size_t)kb * 64 * D_ + krow * D_ + kd0;
        const float* vg = V + base + (size_t)kb * 64 * D_ + vkey * D_ + vd0;
        const int kb0 = (half << 12);              // buffer 0, K
        const int vb0 = 16384 + (half << 12);      // buffer 0, V
        float4_ kv0 = *(const float4_*)(kg);
        float4_ kv1 = *(const float4_*)(kg + 4);
        float4_ kv2 = *(const float4_*)(kg + 8);
        float4_ kv3 = *(const float4_*)(kg + 12);
        short8 kw0, kw1;
#pragma unroll
        for (int e = 0; e < 4; ++e) {
            kw0[e] = f2h(kv0[e]); kw0[e + 4] = f2h(kv1[e]);
            kw1[e] = f2h(kv2[e]); kw1[e + 4] = f2h(kv3[e]);
        }
        *(short8*)&lds[kb0 + swz(krow, kchunk * 2)]     = kw0;
        *(short8*)&lds[kb0 + swz(krow, kchunk * 2 + 1)] = kw1;
        float4_ vv[4];
#pragma unroll
        for (int r = 0; r < 4; ++r) vv[r] = *(const float4_*)(vg + r * 4);
#pragma unroll
        for (int r = 0; r < 4; ++r)
#pragma unroll
            for (int e = 0; e < 4; ++e) {
                int d = vd0 + r * 4 + e;
                lds[vb0 + swz(d, vkey >> 3) + (vkey & 7)] = f2bf(vv[r][e]);
            }
    }

    float biasc[4], biasn[4] = {0.f, 0.f, 0.f, 0.f};
#pragma unroll
    for (int t = 0; t < 4; ++t)
        biasc[t] = kill ? -2.0e6f
                        : -1.0e6f * LOG2E * (1.0f - Msk[(size_t)b * S_ + kb * 64 + t * 16 + c]);

    // ---- Q A-frags in fp16, log2e folded into Q ----
    half8_ qa0, qa1;
    {
        const float* qp = Q + base + (size_t)(qb * 64 + w4 * 16 + c) * D_ + quad * 8;
        float4_ q0 = *(const float4_*)(qp);
        float4_ q1 = *(const float4_*)(qp + 4);
        float4_ q2 = *(const float4_*)(qp + 32);
        float4_ q3 = *(const float4_*)(qp + 36);
#pragma unroll
        for (int e = 0; e < 4; ++e) {
            qa0[e]     = (_Float16)(q0[e] * LOG2E);
            qa0[e + 4] = (_Float16)(q1[e] * LOG2E);
            qa1[e]     = (_Float16)(q2[e] * LOG2E);
            qa1[e + 4] = (_Float16)(q3[e] * LOG2E);
        }
    }

    float4_ o[4];
    float l_part[4];
#pragma unroll
    for (int t = 0; t < 4; ++t) { o[t][0] = 0.f; o[t][1] = 0.f; o[t][2] = 0.f; o[t][3] = 0.f; }
#pragma unroll
    for (int j = 0; j < 4; ++j) l_part[j] = 0.f;

    int foff_lo[4], foff_hi[4];
#pragma unroll
    for (int t = 0; t < 4; ++t) {
        foff_lo[t] = swz(t * 16 + c, quad);
        foff_hi[t] = swz(t * 16 + c, quad + 4);
    }
    const int pwoff = 32768 + (wave << 10);
    const int prd0  = pwoff + swz(c, quad);
    const int prd1  = pwoff + swz(c, quad + 4);

    int cur = 0;
    for (int it2 = 0; it2 < niter; ++it2) {
        // pick next tile (registers only)
        bool nkill = true;
        if (it2 + 1 < niter && mine) { kb = __builtin_ctz(mine); mine &= mine - 1; nkill = false; }
        const bool stage = (it2 + 1 < niter) && !nkill;

        __syncthreads();   // prev readers of buf cur^1 done; its rewrite is legal

        // issue next-tile K loads early (latency hides under QK MFMA)
        const float* kg = nullptr; const float* vg = nullptr;
        float4_ kv0, kv1, kv2, kv3;
        if (stage) {
            kg = K + base + (size_t)kb * 64 * D_ + krow * D_ + kd0;
            vg = V + base + (size_t)kb * 64 * D_ + vkey * D_ + vd0;
            kv0 = *(const float4_*)(kg);
            kv1 = *(const float4_*)(kg + 4);
            kv2 = *(const float4_*)(kg + 8);
            kv3 = *(const float4_*)(kg + 12);
        }
        if (it2 + 1 < niter) {
#pragma unroll
            for (int t = 0; t < 4; ++t)
                biasn[t] = nkill ? -2.0e6f
                                 : -1.0e6f * LOG2E * (1.0f - Msk[(size_t)b * S_ + kb * 64 + t * 16 + c]);
        }

        const int kbase = (cur << 13) + (half << 12);
        const int vbase = 16384 + kbase;
        const int nb13  = ((cur ^ 1) << 13) + (half << 12);   // next-buffer base

        // ---- scores (log2e in Q): 8 fp16 MFMA from this half's K tile ----
        float4_ sc[4];
#pragma unroll
        for (int t = 0; t < 4; ++t) { sc[t][0] = 0.f; sc[t][1] = 0.f; sc[t][2] = 0.f; sc[t][3] = 0.f; }
        __builtin_amdgcn_s_setprio(1);
#pragma unroll
        for (int t = 0; t < 4; ++t) {
            half8_ kf0 = __builtin_bit_cast(half8_, *(const short8*)&lds[kbase + foff_lo[t]]);
            half8_ kf1 = __builtin_bit_cast(half8_, *(const short8*)&lds[kbase + foff_hi[t]]);
            sc[t] = __builtin_amdgcn_mfma_f32_16x16x32_f16(qa0, kf0, sc[t], 0, 0, 0);
            sc[t] = __builtin_amdgcn_mfma_f32_16x16x32_f16(qa1, kf1, sc[t], 0, 0, 0);
        }
        __builtin_amdgcn_s_setprio(0);

        // ---- P = exp2(s + bias'); per-lane l partial; P -> swizzled per-wave tile ----
#pragma unroll
        for (int t = 0; t < 4; ++t) {
            const int cg = (t << 1) + (c >> 3);      // column granule of t*16+c
#pragma unroll
            for (int j = 0; j < 4; ++j) {
                float p = __builtin_amdgcn_exp2f(sc[t][j] + biasc[t]);
                l_part[j] += p;
                const int row = quad * 4 + j;
                lds[pwoff + (row << 6) + (((cg ^ row) & 7) << 3) + (c & 7)] = f2bf_t(p);
            }
        }

        // ---- write next K tile (fp16), issue next V loads ----
        float4_ vv[4];
        if (stage) {
            short8 kw0, kw1;
#pragma unroll
            for (int e = 0; e < 4; ++e) {
                kw0[e] = f2h(kv0[e]); kw0[e + 4] = f2h(kv1[e]);
                kw1[e] = f2h(kv2[e]); kw1[e + 4] = f2h(kv3[e]);
            }
            *(short8*)&lds[nb13 + swz(krow, kchunk * 2)]     = kw0;
            *(short8*)&lds[nb13 + swz(krow, kchunk * 2 + 1)] = kw1;
#pragma unroll
            for (int r = 0; r < 4; ++r) vv[r] = *(const float4_*)(vg + r * 4);
        }

        // ---- P A-frags (same-wave DS ordering) ----
        short8 pa0 = *(const short8*)&lds[prd0];
        short8 pa1 = *(const short8*)&lds[prd1];

        // ---- O += P * V (bf16) from this half's V tile ----
        __builtin_amdgcn_s_setprio(1);
#pragma unroll
        for (int t = 0; t < 4; ++t) {
            short8 vb0 = *(const short8*)&lds[vbase + foff_lo[t]];
            short8 vb1 = *(const short8*)&lds[vbase + foff_hi[t]];
            o[t] = __builtin_amdgcn_mfma_f32_16x16x32_bf16(pa0, vb0, o[t], 0, 0, 0);
            o[t] = __builtin_amdgcn_mfma_f32_16x16x32_bf16(pa1, vb1, o[t], 0, 0, 0);
        }
        __builtin_amdgcn_s_setprio(0);

        // ---- write next V tile (bf16, transposed scatter) ----
        if (stage) {
            const int vnb = 16384 + nb13;
#pragma unroll
            for (int r = 0; r < 4; ++r)
#pragma unroll
                for (int e = 0; e < 4; ++e) {
                    int d = vd0 + r * 4 + e;
                    lds[vnb + swz(d, vkey >> 3) + (vkey & 7)] = f2bf(vv[r][e]);
                }
        }

#pragma unroll
        for (int t = 0; t < 4; ++t) biasc[t] = biasn[t];
        cur ^= 1;
    }

    // ---- in-LDS merge: half1 publishes (o, l); half0 adds, normalizes, stores ----
    __syncthreads();
    float* fl = (float*)lds;                  // overlays K/V/P area
    if (half == 1) {
        const int idx = ((wave - 4) * 64 + lane) * 21;   // 21-stride: conflict-free
#pragma unroll
        for (int t = 0; t < 4; ++t)
#pragma unroll
            for (int j = 0; j < 4; ++j) fl[idx + t * 4 + j] = o[t][j];
#pragma unroll
        for (int j = 0; j < 4; ++j) fl[idx + 16 + j] = l_part[j];
    }
    __syncthreads();
    if (half == 0) {
        const int idx = (wave * 64 + lane) * 21;
#pragma unroll
        for (int j = 0; j < 4; ++j) {
            float rs = l_part[j] + fl[idx + 16 + j];
            rs += __shfl_xor(rs, 1);
            rs += __shfl_xor(rs, 2);
            rs += __shfl_xor(rs, 4);
            rs += __shfl_xor(rs, 8);
            float inv = 1.0f / rs;
            size_t rowoff = base + (size_t)(qb * 64 + w4 * 16 + quad * 4 + j) * D_;
#pragma unroll
            for (int t = 0; t < 4; ++t)
                O[rowoff + t * 16 + c] = (o[t][j] + fl[idx + t * 4 + j]) * inv;
        }
    }
}

extern "C" void kernel_launch(void* const* d_in, const int* in_sizes, int n_in,
                              void* d_out, int out_size, void* d_ws, size_t ws_size,
                              hipStream_t stream) {
    const float* q   = (const float*)d_in[0];
    const float* k   = (const float*)d_in[1];
    const float* v   = (const float*)d_in[2];
    const float* msk = (const float*)d_in[3];
    const int*   mat = (const int*)d_in[4];
    float*       out = (float*)d_out;

    (void)d_ws; (void)ws_size;   // workspace deliberately unused (re-poison test)

    attn_direct<<<dim3(NB_ * B_ * H_), dim3(512), 0, stream>>>(q, k, v, msk, mat, out);
}

// Round 5
// 106.791 us; speedup vs baseline: 1.5486x; 1.5486x over previous
//
#include <hip/hip_runtime.h>

// Block-sparse attention, fp16 QK + bf16 PV MFMA, deferred softmax,
// FUSED 2-way key split: one 512-thr WG (8 waves) per (qb, bh).
// This revision (T12 port): swapped QK^T (mfma(K,Q) -> S^T) so P lives in
// registers; PV A-frags rebuilt via v_cvt_pk_bf16_f32 + permlane16/32_swap
// (VALU pipe) -- the P LDS round-trip (16 b16 writes + 2 b128 reads + lgkm
// dependency) is GONE. P-LDS freed: 80 -> 64 KB. l is one scalar per lane.
// fp32 in/out. B=2 H=8 S=2048 D=64, BLOCK=64, nb=32.

typedef __attribute__((ext_vector_type(8))) short short8;
typedef __attribute__((ext_vector_type(4))) short short4_;
typedef __attribute__((ext_vector_type(4))) float float4_;
typedef __attribute__((ext_vector_type(4))) unsigned int uint4_;
typedef __attribute__((ext_vector_type(8))) _Float16 half8_;

#define B_   2
#define H_   8
#define S_   2048
#define D_   64
#define NB_  32
#define KP   72          // padded stride (fallback kernel only)
#define KP2  66          // preconvert staging stride
#define LOG2E 1.4426950408889634f

__device__ __forceinline__ short f2bf(float f) {            // RNE float->bf16 bits
    union { float f; unsigned int u; } x; x.f = f;
    unsigned int r = x.u + 0x7FFFu + ((x.u >> 16) & 1u);
    return (short)(r >> 16);
}
__device__ __forceinline__ float bf2f(short s) {
    union { unsigned int u; float f; } x; x.u = ((unsigned int)(unsigned short)s) << 16;
    return x.f;
}
__device__ __forceinline__ short f2h(float f) {
    _Float16 h = (_Float16)f;
    return __builtin_bit_cast(short, h);
}
// XOR-swizzled offset for a 64-col-short tile stored in granules of 8 shorts.
__device__ __forceinline__ int swz(int row, int gran) {
    return (row << 6) + (((gran ^ row) & 7) << 3);
}
// async global->LDS DMA, 16 B/lane
__device__ __forceinline__ void gload16(const short* g, short* l) {
    __builtin_amdgcn_global_load_lds(
        (const __attribute__((address_space(1))) void*)g,
        (__attribute__((address_space(3))) void*)l, 16, 0, 0);
}
__device__ __forceinline__ unsigned int cvt_pk_bf16(float lo, float hi) {
    unsigned int r;
    asm("v_cvt_pk_bf16_f32 %0, %1, %2" : "=v"(r) : "v"(lo), "v"(hi));
    return r;
}
// bijective XCD-clustering remap of a flat 512-WG id -> (bh, idx)
__device__ __forceinline__ void wg_remap(int n, int& bh, int& idx) {
    const int xcd = n & 7;
    const int sub = n >> 3;          // 0..63
    bh  = (xcd << 1) + (sub & 1);
    idx = sub >> 1;                  // 0..31
}

// ---------------- pre-pass: K -> fp16*log2e swizzled tiles, V -> transposed
// swizzled bf16 tiles (LDS-staged). Tiles byte-identical to the LDS image. ----
__global__ __launch_bounds__(256)
void preconvert_kernel(const float* __restrict__ K, const float* __restrict__ V,
                       short* __restrict__ Khf, short* __restrict__ Vtb) {
    __shared__ short vn[64 * KP2];
    const int tid = threadIdx.x;
    int bh, kt;
    wg_remap(blockIdx.x, bh, kt);
    const size_t src = ((size_t)bh * S_ + kt * 64) * D_;
    const size_t dst = ((size_t)(bh * NB_ + kt)) << 12;

#pragma unroll
    for (int it = 0; it < 4; ++it) {
        int i = tid + it * 256;
        int row = i >> 4, c4 = (i & 15) * 4;
        float4_ kv = *(const float4_*)(K + src + row * D_ + c4);
        short4_ kh;
#pragma unroll
        for (int e = 0; e < 4; ++e) kh[e] = f2h(kv[e] * LOG2E);   // fold log2e
        *(short4_*)(Khf + dst + swz(row, c4 >> 3) + (c4 & 7)) = kh;
        float4_ vv = *(const float4_*)(V + src + row * D_ + c4);
        short4_ vb;
#pragma unroll
        for (int e = 0; e < 4; ++e) vb[e] = f2bf(vv[e]);
        *(short4_*)&vn[row * KP2 + c4] = vb;
    }
    __syncthreads();
#pragma unroll
    for (int it = 0; it < 2; ++it) {
        int i = tid + it * 256;
        int d = i >> 3, g = i & 7;
        short8 o;
#pragma unroll
        for (int e = 0; e < 8; ++e) o[e] = vn[(g * 8 + e) * KP2 + d];
        *(short8*)(Vtb + dst + swz(d, g)) = o;
    }
}

// ---------------- main: 512-thr WG, swapped-QK in-register-P ----------------
__global__ __launch_bounds__(512, 4)
void attn_fused(const float* __restrict__ Q,
                const float* __restrict__ Msk,
                const int* __restrict__ Mat,
                float* __restrict__ O,
                const short* __restrict__ Khf_g,
                const short* __restrict__ Vtb_g) {
    // shorts: K dbuf [buf][half][4096] @0 | V dbuf @16384. 64 KB -> 2 WG/CU.
    __shared__ __align__(16) short lds[32768];

    const int tid  = threadIdx.x;
    const int wave = tid >> 6;        // 0..7
    const int half = wave >> 2;       // key half 0/1
    const int w4   = wave & 3;        // 16-row q tile
    const int lane = tid & 63;
    const int c    = lane & 15;
    const int quad = lane >> 4;
    const bool oddq = (quad & 1) != 0;

    int bh, qb;
    wg_remap(blockIdx.x, bh, qb);
    const int b  = bh / H_;
    const size_t base = (size_t)bh * S_ * D_;

    // ---- active-block bitmask; this half takes alternating entries ----
    unsigned long long bmv = __ballot(Mat[qb * NB_ + (lane & 31)] != 0);
    unsigned int mb = (unsigned int)(bmv & 0xFFFFFFFFull);
    const int nact  = __popc(mb);
    const int niter = (nact + 1) >> 1;
    unsigned int mine = 0;
    {
        unsigned int tb2 = mb; int idx = 0;
        while (tb2) {
            int k = __builtin_ctz(tb2); tb2 &= tb2 - 1;
            if ((idx & 1) == half) mine |= (1u << k);
            ++idx;
        }
    }

    // ---- prologue: stage first tile (always a REAL block) ----
    int kb_c; bool kill_c;
    if (mine) { kb_c = __builtin_ctz(mine); mine &= mine - 1; kill_c = false; }
    else      { kb_c = __builtin_ctz(mb); kill_c = true; }
    {
        const size_t tb = ((size_t)(bh * NB_ + kb_c)) << 12;
        const int kd = (half << 12) + (w4 << 10);
        const short* gk = Khf_g + tb + (w4 << 10) + lane * 8;
        const short* gv = Vtb_g + tb + (w4 << 10) + lane * 8;
        gload16(gk,       &lds[kd]);
        gload16(gk + 512, &lds[kd + 512]);
        gload16(gv,       &lds[16384 + kd]);
        gload16(gv + 512, &lds[16384 + kd + 512]);
    }

    // ---- Q A-frags in fp16 (K carries log2e) ----
    half8_ qa0, qa1;
    {
        const float* qp = Q + base + (size_t)(qb * 64 + w4 * 16 + c) * D_ + quad * 8;
        float4_ q0 = *(const float4_*)(qp);
        float4_ q1 = *(const float4_*)(qp + 4);
        float4_ q2 = *(const float4_*)(qp + 32);
        float4_ q3 = *(const float4_*)(qp + 36);
#pragma unroll
        for (int e = 0; e < 4; ++e) {
            qa0[e]     = (_Float16)q0[e];
            qa0[e + 4] = (_Float16)q1[e];
            qa1[e]     = (_Float16)q2[e];
            qa1[e + 4] = (_Float16)q3[e];
        }
    }

    float4_ o[4];
    float l_sum = 0.f;
#pragma unroll
    for (int t = 0; t < 4; ++t) { o[t][0] = 0.f; o[t][1] = 0.f; o[t][2] = 0.f; o[t][3] = 0.f; }

    int foff_lo[4], foff_hi[4];
#pragma unroll
    for (int t = 0; t < 4; ++t) {
        foff_lo[t] = swz(t * 16 + c, quad);
        foff_hi[t] = swz(t * 16 + c, quad + 4);
    }

    int cur = 0;
    for (int it2 = 0; it2 < niter; ++it2) {
        int kb_n = kb_c; bool kill_n = true;
        if (it2 + 1 < niter && mine) { kb_n = __builtin_ctz(mine); mine &= mine - 1; kill_n = false; }

        __syncthreads();   // tile it2 resident; buf cur^1 reusable

        if (it2 + 1 < niter && !kill_n) {
            const size_t tb = ((size_t)(bh * NB_ + kb_n)) << 12;
            const int kd = ((cur ^ 1) << 13) + (half << 12) + (w4 << 10);
            const short* gk = Khf_g + tb + (w4 << 10) + lane * 8;
            const short* gv = Vtb_g + tb + (w4 << 10) + lane * 8;
            gload16(gk,       &lds[kd]);
            gload16(gk + 512, &lds[kd + 512]);
            gload16(gv,       &lds[16384 + kd]);
            gload16(gv + 512, &lds[16384 + kd + 512]);
        }

        const int kbase = (cur << 13) + (half << 12);
        const int vbase = 16384 + kbase;

        // ---- bias for CURRENT tile (per-key now): 4 x float4, L2-hot ----
        float4_ mskv[4];
        if (!kill_c) {
#pragma unroll
            for (int t = 0; t < 4; ++t)
                mskv[t] = *(const float4_*)(Msk + (size_t)b * S_ + kb_c * 64 + t * 16 + quad * 4);
        }

        // ---- swapped scores: sc[t] = K_tile_t * Q^T  (rows = keys, cols = q) ----
        float4_ sc[4];
#pragma unroll
        for (int t = 0; t < 4; ++t) { sc[t][0] = 0.f; sc[t][1] = 0.f; sc[t][2] = 0.f; sc[t][3] = 0.f; }
        __builtin_amdgcn_s_setprio(1);
#pragma unroll
        for (int t = 0; t < 4; ++t) {
            half8_ kf0 = __builtin_bit_cast(half8_, *(const short8*)&lds[kbase + foff_lo[t]]);
            half8_ kf1 = __builtin_bit_cast(half8_, *(const short8*)&lds[kbase + foff_hi[t]]);
            sc[t] = __builtin_amdgcn_mfma_f32_16x16x32_f16(kf0, qa0, sc[t], 0, 0, 0);
            sc[t] = __builtin_amdgcn_mfma_f32_16x16x32_f16(kf1, qa1, sc[t], 0, 0, 0);
        }
        __builtin_amdgcn_s_setprio(0);

        // ---- P = exp2(s + bias) fully in-register; pack to bf16 pairs ----
        // lane(c,quad) j-th value = P[key = t*16+quad*4+j][q = c]
        unsigned int r_[4][2];
#pragma unroll
        for (int t = 0; t < 4; ++t) {
            float p[4];
#pragma unroll
            for (int j = 0; j < 4; ++j) {
                float bj = kill_c ? -2.0e6f : -1.0e6f * LOG2E * (1.0f - mskv[t][j]);
                p[j] = __builtin_amdgcn_exp2f(sc[t][j] + bj);
                l_sum += p[j];
            }
            r_[t][0] = cvt_pk_bf16(p[0], p[1]);
            r_[t][1] = cvt_pk_bf16(p[2], p[3]);
        }

        // ---- route packed P into PV A-frags via permlane (no LDS) ----
        // step 1: per (t,s) duplicate pair halves: La = lower-quad-of-pair, Lb = upper
        unsigned int La[4][2], Lb[4][2];
#pragma unroll
        for (int t = 0; t < 4; ++t)
#pragma unroll
            for (int s = 0; s < 2; ++s) {
                unsigned int x = r_[t][s], y = r_[t][s];
                asm("v_permlane16_swap_b32 %0, %1" : "+v"(x), "+v"(y));
                La[t][s] = x;   // quads {0,1}: quad0 data; {2,3}: quad2 data
                Lb[t][s] = y;   // quads {0,1}: quad1 data; {2,3}: quad3 data
            }
        // step 2: cross-pair swap + per-quad select -> pa0 (k 0..31), pa1 (k 32..63)
        uint4_ w0, w1;
#pragma unroll
        for (int s = 0; s < 2; ++s) {
            unsigned int d0, s1;
            d0 = La[0][s]; s1 = La[1][s];
            asm("v_permlane32_swap_b32 %0, %1" : "+v"(d0), "+v"(s1));
            w0[s] = oddq ? s1 : d0;
            d0 = Lb[0][s]; s1 = Lb[1][s];
            asm("v_permlane32_swap_b32 %0, %1" : "+v"(d0), "+v"(s1));
            w0[2 + s] = oddq ? s1 : d0;
            d0 = La[2][s]; s1 = La[3][s];
            asm("v_permlane32_swap_b32 %0, %1" : "+v"(d0), "+v"(s1));
            w1[s] = oddq ? s1 : d0;
            d0 = Lb[2][s]; s1 = Lb[3][s];
            asm("v_permlane32_swap_b32 %0, %1" : "+v"(d0), "+v"(s1));
            w1[2 + s] = oddq ? s1 : d0;
        }
        short8 pa0 = __builtin_bit_cast(short8, w0);
        short8 pa1 = __builtin_bit_cast(short8, w1);

        // ---- O += P * V (bf16) ----
        __builtin_amdgcn_s_setprio(1);
#pragma unroll
        for (int t = 0; t < 4; ++t) {
            short8 vb0 = *(const short8*)&lds[vbase + foff_lo[t]];
            short8 vb1 = *(const short8*)&lds[vbase + foff_hi[t]];
            o[t] = __builtin_amdgcn_mfma_f32_16x16x32_bf16(pa0, vb0, o[t], 0, 0, 0);
            o[t] = __builtin_amdgcn_mfma_f32_16x16x32_bf16(pa1, vb1, o[t], 0, 0, 0);
        }
        __builtin_amdgcn_s_setprio(0);

        kb_c = kb_n; kill_c = kill_n; cur ^= 1;
    }

    // ---- in-LDS merge: half1 publishes (o, l); half0 adds, normalizes, stores ----
    __syncthreads();
    float* fl = (float*)lds;
    if (half == 1) {
        const int idx = ((wave - 4) * 64 + lane) * 17;   // odd stride: bank-walk
#pragma unroll
        for (int t = 0; t < 4; ++t)
#pragma unroll
            for (int j = 0; j < 4; ++j) fl[idx + t * 4 + j] = o[t][j];
        fl[idx + 16] = l_sum;
    }
    __syncthreads();
    if (half == 0) {
        const int idx = (wave * 64 + lane) * 17;
        float lt = l_sum + fl[idx + 16];          // both halves' partial row sums
        lt += __shfl_xor(lt, 16);
        lt += __shfl_xor(lt, 32);                 // every lane: total for q-row = c
#pragma unroll
        for (int j = 0; j < 4; ++j) {
            float rs = __shfl(lt, quad * 4 + j, 16);   // total for row quad*4+j
            float inv = 1.0f / rs;
            size_t rowoff = base + (size_t)(qb * 64 + w4 * 16 + quad * 4 + j) * D_;
#pragma unroll
            for (int t = 0; t < 4; ++t)
                O[rowoff + t * 16 + c] = (o[t][j] + fl[idx + t * 4 + j]) * inv;
        }
    }
}

// ---------------- fallback (no workspace): bf16 hi/lo LDS-staging kernel ----------------
__global__ __launch_bounds__(256, 2)
void attn_mfma_fb(const float* __restrict__ Q,
                  const float* __restrict__ K,
                  const float* __restrict__ V,
                  const float* __restrict__ Msk,
                  const int* __restrict__ Mat,
                  float* __restrict__ O) {
    __shared__ __align__(16) short lds[4 * 64 * KP];
    short* Khi = lds;
    short* Klo = lds + 64 * KP;
    short* Vt  = lds + 2 * 64 * KP;
    short* Pl  = lds + 3 * 64 * KP;

    const int tid  = threadIdx.x;
    const int wave = tid >> 6;
    const int lane = tid & 63;
    const int c    = lane & 15;
    const int quad = lane >> 4;

    const int qb = blockIdx.x;
    const int bh = blockIdx.y;
    const int b  = bh / H_;
    const size_t base = (size_t)bh * S_ * D_;

    short8 qh0, qh1, ql0, ql1;
    {
        const float* qp = Q + base + (size_t)(qb * 64 + wave * 16 + c) * D_ + quad * 8;
#pragma unroll
        for (int e = 0; e < 8; ++e) {
            float f0 = qp[e], f1 = qp[e + 32];
            qh0[e] = f2bf(f0); ql0[e] = f2bf(f0 - bf2f(qh0[e]));
            qh1[e] = f2bf(f1); ql1[e] = f2bf(f1 - bf2f(qh1[e]));
        }
    }

    float4_ o[4];
    float l_part[4];
#pragma unroll
    for (int t = 0; t < 4; ++t) { o[t][0] = 0.f; o[t][1] = 0.f; o[t][2] = 0.f; o[t][3] = 0.f; }
#pragma unroll
    for (int j = 0; j < 4; ++j) l_part[j] = 0.f;

    for (int kb = 0; kb < NB_; ++kb) {
        if (Mat[qb * NB_ + kb] == 0) continue;

        __syncthreads();
        {
            const float* kg = K + base + (size_t)kb * 64 * D_;
            const float* vg = V + base + (size_t)kb * 64 * D_;
#pragma unroll
            for (int it = 0; it < 4; ++it) {
                int i = tid + it * 256;
                int row = i >> 4, c4 = (i & 15) * 4;
                float4_ kv = *(const float4_*)(kg + row * D_ + c4);
                short4_ hi, lo;
#pragma unroll
                for (int e = 0; e < 4; ++e) {
                    hi[e] = f2bf(kv[e]);
                    lo[e] = f2bf(kv[e] - bf2f(hi[e]));
                }
                *(short4_*)&Khi[row * KP + c4] = hi;
                *(short4_*)&Klo[row * KP + c4] = lo;
                float4_ vv = *(const float4_*)(vg + row * D_ + c4);
#pragma unroll
                for (int e = 0; e < 4; ++e) Vt[(c4 + e) * KP + row] = f2bf(vv[e]);
            }
        }
        __syncthreads();

        float4_ sc[4];
#pragma unroll
        for (int t = 0; t < 4; ++t) { sc[t][0] = 0.f; sc[t][1] = 0.f; sc[t][2] = 0.f; sc[t][3] = 0.f; }
#pragma unroll
        for (int t = 0; t < 4; ++t) {
            const short* kph = &Khi[(t * 16 + c) * KP + quad * 8];
            const short* kpl = &Klo[(t * 16 + c) * KP + quad * 8];
            short8 kh0 = *(const short8*)(kph);
            short8 kh1 = *(const short8*)(kph + 32);
            short8 kl0 = *(const short8*)(kpl);
            short8 kl1 = *(const short8*)(kpl + 32);
            sc[t] = __builtin_amdgcn_mfma_f32_16x16x32_bf16(qh0, kh0, sc[t], 0, 0, 0);
            sc[t] = __builtin_amdgcn_mfma_f32_16x16x32_bf16(qh1, kh1, sc[t], 0, 0, 0);
            sc[t] = __builtin_amdgcn_mfma_f32_16x16x32_bf16(qh0, kl0, sc[t], 0, 0, 0);
            sc[t] = __builtin_amdgcn_mfma_f32_16x16x32_bf16(qh1, kl1, sc[t], 0, 0, 0);
            sc[t] = __builtin_amdgcn_mfma_f32_16x16x32_bf16(ql0, kh0, sc[t], 0, 0, 0);
            sc[t] = __builtin_amdgcn_mfma_f32_16x16x32_bf16(ql1, kh1, sc[t], 0, 0, 0);
        }

        short* Pw = Pl + wave * 16 * KP;
#pragma unroll
        for (int t = 0; t < 4; ++t) {
            float bias = -1.0e6f * (1.0f - Msk[(size_t)b * S_ + kb * 64 + t * 16 + c]);
#pragma unroll
            for (int j = 0; j < 4; ++j) {
                float p = __expf(sc[t][j] + bias);
                l_part[j] += p;
                Pw[(quad * 4 + j) * KP + t * 16 + c] = f2bf(p);
            }
        }

        const short* pp = Pl + wave * 16 * KP + c * KP + quad * 8;
        short8 pa0 = *(const short8*)(pp);
        short8 pa1 = *(const short8*)(pp + 32);

#pragma unroll
        for (int t = 0; t < 4; ++t) {
            const short* vp = &Vt[(t * 16 + c) * KP + quad * 8];
            short8 vb0 = *(const short8*)(vp);
            short8 vb1 = *(const short8*)(vp + 32);
            o[t] = __builtin_amdgcn_mfma_f32_16x16x32_bf16(pa0, vb0, o[t], 0, 0, 0);
            o[t] = __builtin_amdgcn_mfma_f32_16x16x32_bf16(pa1, vb1, o[t], 0, 0, 0);
        }
    }

#pragma unroll
    for (int j = 0; j < 4; ++j) {
        float rs = l_part[j];
        rs += __shfl_xor(rs, 1);
        rs += __shfl_xor(rs, 2);
        rs += __shfl_xor(rs, 4);
        rs += __shfl_xor(rs, 8);
        float inv = 1.0f / rs;
        size_t rowoff = base + (size_t)(qb * 64 + wave * 16 + quad * 4 + j) * D_;
#pragma unroll
        for (int t = 0; t < 4; ++t)
            O[rowoff + t * 16 + c] = o[t][j] * inv;
    }
}

extern "C" void kernel_launch(void* const* d_in, const int* in_sizes, int n_in,
                              void* d_out, int out_size, void* d_ws, size_t ws_size,
                              hipStream_t stream) {
    const float* q   = (const float*)d_in[0];
    const float* k   = (const float*)d_in[1];
    const float* v   = (const float*)d_in[2];
    const float* msk = (const float*)d_in[3];
    const int*   mat = (const int*)d_in[4];
    float*       out = (float*)d_out;

    const size_t elems = (size_t)B_ * H_ * S_ * D_;      // 2,097,152
    const size_t need  = 2 * elems * sizeof(short);      // khf + vtb = 8.4 MB
    const int use_pre  = (ws_size >= need) ? 1 : 0;

    short* khf = (short*)d_ws;
    short* vtb = khf + elems;

    if (use_pre) {
        preconvert_kernel<<<dim3(NB_ * B_ * H_), dim3(256), 0, stream>>>(k, v, khf, vtb);
        attn_fused<<<dim3(NB_ * B_ * H_), dim3(512), 0, stream>>>(q, msk, mat, out, khf, vtb);
    } else {
        dim3 grid(NB_, B_ * H_);
        attn_mfma_fb<<<grid, dim3(256), 0, stream>>>(q, k, v, msk, mat, out);
    }
}